// Round 4
// baseline (433.778 us; speedup 1.0000x reference)
//
#include <hip/hip_runtime.h>

// TimeGraphNet [64,1024,1200] f32 -> softmax [64,3].
//
// R3: overlap-friendly streaming.
//  K1 fused: 128-thread block stages 4 rows into LDS (19.5 KB -> 8 blocks/CU
//     resident, staggered phases), ONE barrier, then each wave computes 2 rows
//     (lane&31 = pool1 window, lane>>5 = row-within-wave): conv1+pool1 from
//     registers, conv2/pool2/conv3 via in-wave __shfl (no extra barriers, no
//     serial funnel). Writes feat[row].
//  K2 classifier: 64 blocks, 3x dot-1024 + softmax (exact since R0).
//
// Per-row math (verified exact R0-R2):
//  y1[j] = relu(b1 + sum_{k=0..9} w1[k]*x[8j-1+k]), j=0..149, zero pad
//  p1[m] = max(y1[5m..5m+4])                                   (30 vals)
//  y2[j] = relu(b2 + sum_{k=0..2} w2[k]*p1[3j+k]), j=0..9
//  p2 = {max(y2[0],y2[1]), max(y2[2..4]), max(y2[5..7]), max(y2[8],y2[9])}
//  feat = relu(b3 + dot(w3, p2))

#define NROWS 65536
#define ROWS_PER_BLOCK 4
#define STRIDE_F 1220              // LDS row stride in floats (pad: !=0 mod 32)
#define STRIDE_F4 305
#define NBLOCKS (NROWS / ROWS_PER_BLOCK)   // 16384

__global__ __launch_bounds__(128, 4) void fused_chain_kernel(
    const float* __restrict__ input,
    const float* __restrict__ w1g, const float* __restrict__ b1g,
    const float* __restrict__ w2g, const float* __restrict__ b2g,
    const float* __restrict__ w3g, const float* __restrict__ b3g,
    float* __restrict__ feat)
{
    __shared__ __align__(16) float xs[ROWS_PER_BLOCK * STRIDE_F]; // 19520 B

    const int tid = threadIdx.x;
    const int blk = blockIdx.x;

    // Stage 4 rows (4800 floats = 1200 float4), coalesced.
    const float4* src = (const float4*)(input + (size_t)blk * 4800);
    #pragma unroll
    for (int it = 0; it < 10; ++it) {
        const int i = tid + it * 128;
        if (i < 1200) {
            const float4 vv = src[i];
            const int r = i / 300;
            const int c4 = i - r * 300;
            ((float4*)xs)[r * STRIDE_F4 + c4] = vv;
        }
    }

    float w1[10];
    #pragma unroll
    for (int k = 0; k < 10; ++k) w1[k] = w1g[k];
    const float b1 = b1g[0];

    __syncthreads();

    // Wave (64 lanes) handles 2 rows: half = lane>>5, window w = lane&31.
    const int lane = tid & 63;
    const int wave = tid >> 6;                 // 0..1
    const int half = lane >> 5;                // 0..1
    const int w = lane & 31;                   // window (valid < 30)
    const int rib = wave * 2 + half;           // row in block 0..3

    const float* xr = xs + rib * STRIDE_F + w * 40;
    float pmax = 0.0f;                         // relu floor folded into pool
    if (w < 30) {
        float v[42];                           // v[m] = x[40w-1+m]
        v[0] = (w == 0) ? 0.0f : xr[-1];
        #pragma unroll
        for (int m = 1; m <= 40; ++m) v[m] = xr[m - 1];
        v[41] = (w == 29) ? 0.0f : xr[40];

        #pragma unroll
        for (int i = 0; i < 5; ++i) {
            float acc = b1;
            #pragma unroll
            for (int k = 0; k < 10; ++k) acc = fmaf(w1[k], v[8 * i + k], acc);
            pmax = fmaxf(pmax, acc);
        }
    }

    // conv2 (K=3,s=3) via in-wave shuffles: lanes base+j (j<10) hold y2[j].
    const int base = lane & 32;
    const int jj = (w < 10) ? w : 9;           // keep shfl src in range
    const float pa = __shfl(pmax, base + 3 * jj, 64);
    const float pb = __shfl(pmax, base + 3 * jj + 1, 64);
    const float pc = __shfl(pmax, base + 3 * jj + 2, 64);
    const float w2a = w2g[0], w2b = w2g[1], w2c = w2g[2];
    const float y2 = fmaxf(fmaf(w2c, pc, fmaf(w2b, pb, fmaf(w2a, pa, b2g[0]))), 0.0f);

    // Gather y2[1..9] into lane base+0; pool2(-inf pad) + conv3 + relu.
    const float t1 = __shfl(y2, base + 1, 64);
    const float t2 = __shfl(y2, base + 2, 64);
    const float t3 = __shfl(y2, base + 3, 64);
    const float t4 = __shfl(y2, base + 4, 64);
    const float t5 = __shfl(y2, base + 5, 64);
    const float t6 = __shfl(y2, base + 6, 64);
    const float t7 = __shfl(y2, base + 7, 64);
    const float t8 = __shfl(y2, base + 8, 64);
    const float t9 = __shfl(y2, base + 9, 64);
    if (w == 0) {
        const float q0 = fmaxf(y2, t1);
        const float q1 = fmaxf(fmaxf(t2, t3), t4);
        const float q2 = fmaxf(fmaxf(t5, t6), t7);
        const float q3 = fmaxf(t8, t9);
        float f = b3g[0];
        f = fmaf(w3g[0], q0, f);
        f = fmaf(w3g[1], q1, f);
        f = fmaf(w3g[2], q2, f);
        f = fmaf(w3g[3], q3, f);
        feat[(size_t)blk * ROWS_PER_BLOCK + rib] = fmaxf(f, 0.0f);
    }
}

__global__ __launch_bounds__(256) void classifier_kernel(
    const float* __restrict__ feat,
    const float* __restrict__ cls_w,
    const float* __restrict__ cls_b,
    float* __restrict__ out)
{
    const int b = blockIdx.x;
    const int tid = threadIdx.x;

    float s0 = 0.0f, s1 = 0.0f, s2 = 0.0f;
    for (int n = tid; n < 1024; n += 256) {
        const float f = feat[b * 1024 + n];
        s0 = fmaf(f, cls_w[n], s0);
        s1 = fmaf(f, cls_w[1024 + n], s1);
        s2 = fmaf(f, cls_w[2048 + n], s2);
    }
    #pragma unroll
    for (int off = 32; off > 0; off >>= 1) {
        s0 += __shfl_down(s0, off, 64);
        s1 += __shfl_down(s1, off, 64);
        s2 += __shfl_down(s2, off, 64);
    }
    __shared__ float red[3][4];
    const int wave = tid >> 6;
    if ((tid & 63) == 0) {
        red[0][wave] = s0;
        red[1][wave] = s1;
        red[2][wave] = s2;
    }
    __syncthreads();
    if (tid == 0) {
        const float l0 = red[0][0] + red[0][1] + red[0][2] + red[0][3] + cls_b[0];
        const float l1 = red[1][0] + red[1][1] + red[1][2] + red[1][3] + cls_b[1];
        const float l2 = red[2][0] + red[2][1] + red[2][2] + red[2][3] + cls_b[2];
        const float m = fmaxf(l0, fmaxf(l1, l2));
        const float e0 = expf(l0 - m);
        const float e1 = expf(l1 - m);
        const float e2 = expf(l2 - m);
        const float inv = 1.0f / (e0 + e1 + e2);
        out[b * 3 + 0] = e0 * inv;
        out[b * 3 + 1] = e1 * inv;
        out[b * 3 + 2] = e2 * inv;
    }
}

extern "C" void kernel_launch(void* const* d_in, const int* in_sizes, int n_in,
                              void* d_out, int out_size, void* d_ws, size_t ws_size,
                              hipStream_t stream) {
    const float* input   = (const float*)d_in[0];
    const float* conv1_w = (const float*)d_in[1];
    const float* conv1_b = (const float*)d_in[2];
    const float* conv2_w = (const float*)d_in[3];
    const float* conv2_b = (const float*)d_in[4];
    const float* conv3_w = (const float*)d_in[5];
    const float* conv3_b = (const float*)d_in[6];
    // d_in[7..10]: gcn params — dead code in the reference.
    const float* cls_w   = (const float*)d_in[11];
    const float* cls_b   = (const float*)d_in[12];

    float* featbuf = (float*)d_ws;        // 65536 floats = 256 KB
    float* out     = (float*)d_out;       // 64*3 fp32

    fused_chain_kernel<<<NBLOCKS, 128, 0, stream>>>(
        input, conv1_w, conv1_b, conv2_w, conv2_b, conv3_w, conv3_b, featbuf);
    classifier_kernel<<<64, 256, 0, stream>>>(featbuf, cls_w, cls_b, out);
}